// Round 9
// baseline (408.985 us; speedup 1.0000x reference)
//
#include <hip/hip_runtime.h>
#include <math.h>

#define N_NODES 100000
#define F_IN    128
#define H1      8
#define C1      16
#define D1      128   // H1*C1
#define NCLS    40
#define NEG     0.2f

typedef unsigned int uint32;
typedef unsigned short ushort16;
typedef float v2f __attribute__((ext_vector_type(2)));

__device__ __forceinline__ ushort16 f2bf(float f) {
    unsigned int u = __float_as_uint(f);
    u += 0x7fffu + ((u >> 16) & 1u);          // round-to-nearest-even
    return (ushort16)(u >> 16);
}
__device__ __forceinline__ float bf_lo(uint32 p) { return __uint_as_float(p << 16); }
__device__ __forceinline__ float bf_hi(uint32 p) { return __uint_as_float(p & 0xffff0000u); }

#define NG 1563   // gemm blocks (64 rows each); each also counts 1024 edges

// ---------------- fused: layer-1 GEMM(+logits) + CSR-count, uniform blocks --
// Every block: (1) issues 4 count-atomics/thread at the top (returns consumed
// only in the epilogue -> ~25us of latency hiding), (2) computes its 64-row
// GEMM tile with W staged in LDS, (3) epilogue: fp8 h1 + logits + rank writes.
__global__ __launch_bounds__(256) void gemm1_count_kernel(
    const float* __restrict__ x, const float* __restrict__ W,
    uint32* __restrict__ h8,            // fp8 rows, N x 32 dwords
    const float* __restrict__ a_src, const float* __restrict__ a_dst,
    float* __restrict__ ssrc, float* __restrict__ sdst,
    const int* __restrict__ ei, int E,
    int* __restrict__ deg, int* __restrict__ rank)
{
    __shared__ float xs[64][132];       // x tile (fp32), later h1 tile
    __shared__ float wt[128][68];       // W chunk transposed: wt[col][k]
    const int bid = blockIdx.x;
    const int tid = threadIdx.x;

    // ---- count slice: load dsts + issue atomics (consume ranks at the end) --
    const long long ebase = (long long)bid * 1024;
    int dste[4], rnk[4];
#pragma unroll
    for (int i = 0; i < 4; ++i) {
        long long e = ebase + tid + i * 256;
        dste[i] = (e < E) ? ei[E + e] : -1;
    }
#pragma unroll
    for (int i = 0; i < 4; ++i)
        rnk[i] = (dste[i] >= 0) ? atomicAdd(&deg[dste[i]], 1) : 0;

    const int row0 = bid * 64;
    // ---- load x tile (coalesced float4) ----
#pragma unroll
    for (int i = 0; i < 8; ++i) {
        int idx = tid + i * 256;      // 0..2047
        int r = idx >> 5, c4 = idx & 31;
        float4 v = make_float4(0.f, 0.f, 0.f, 0.f);
        if (row0 + r < N_NODES)
            v = ((const float4*)x)[(size_t)(row0 + r) * 32 + c4];
        *(float4*)&xs[r][c4 * 4] = v;
    }
    const int cg = tid & 15;
    const int rg = tid >> 4;
    float acc[4][8];
#pragma unroll
    for (int i = 0; i < 4; ++i)
#pragma unroll
        for (int j = 0; j < 8; ++j) acc[i][j] = 0.f;

    const int stc = tid & 127;        // staging: col
    const int sth = tid >> 7;         // staging: k-half (0..1)
#pragma unroll
    for (int chunk = 0; chunk < 2; ++chunk) {
        const int kbase = chunk * 64;
        __syncthreads();              // wt free / x tile ready
#pragma unroll
        for (int kk = 0; kk < 8; ++kk) {
            int k = sth * 32 + kk * 4;
            float4 v;
            v.x = W[(size_t)(kbase + k)     * 128 + stc];
            v.y = W[(size_t)(kbase + k + 1) * 128 + stc];
            v.z = W[(size_t)(kbase + k + 2) * 128 + stc];
            v.w = W[(size_t)(kbase + k + 3) * 128 + stc];
            *(float4*)&wt[stc][k] = v;
        }
        __syncthreads();
        for (int k0 = 0; k0 < 64; k0 += 4) {
            float4 wa[8];
#pragma unroll
            for (int j = 0; j < 8; ++j)
                wa[j] = *(const float4*)&wt[cg + 16 * j][k0];
#pragma unroll
            for (int i = 0; i < 4; ++i) {
                float4 hx = *(const float4*)&xs[rg + 16 * i][kbase + k0];
#pragma unroll
                for (int j = 0; j < 8; ++j) {
                    acc[i][j] = fmaf(hx.x, wa[j].x, acc[i][j]);
                    acc[i][j] = fmaf(hx.y, wa[j].y, acc[i][j]);
                    acc[i][j] = fmaf(hx.z, wa[j].z, acc[i][j]);
                    acc[i][j] = fmaf(hx.w, wa[j].w, acc[i][j]);
                }
            }
        }
    }
    __syncthreads();   // all reads of x tile done
    // ---- write h1 (fp32) back into xs ----
#pragma unroll
    for (int i = 0; i < 4; ++i)
#pragma unroll
        for (int j = 0; j < 8; ++j)
            xs[rg + 16 * i][cg + 16 * j] = acc[i][j];
    __syncthreads();
    // ---- fp8 pack: 64 rows x 16 uint2-groups, 4 tasks/thread ----
#pragma unroll
    for (int t = 0; t < 4; ++t) {
        int task = tid + t * 256;     // 0..1023
        int r = task >> 4, g = task & 15;
        if (row0 + r < N_NODES) {
            float4 a = *(const float4*)&xs[r][8 * g];
            float4 b = *(const float4*)&xs[r][8 * g + 4];
            int p0 = __builtin_amdgcn_cvt_pk_fp8_f32(a.x, a.y, 0, false);
            p0     = __builtin_amdgcn_cvt_pk_fp8_f32(a.z, a.w, p0, true);
            int p1 = __builtin_amdgcn_cvt_pk_fp8_f32(b.x, b.y, 0, false);
            p1     = __builtin_amdgcn_cvt_pk_fp8_f32(b.z, b.w, p1, true);
            uint2 pk; pk.x = (uint32)p0; pk.y = (uint32)p1;
            ((uint2*)h8)[(size_t)(row0 + r) * 16 + g] = pk;
        }
    }
    // ---- logits: 64 rows x 8 heads = 512 tasks, 2 per thread ----
#pragma unroll
    for (int t = 0; t < 2; ++t) {
        int task = tid + t * 256;
        int r = task >> 3, hh = task & 7;
        if (row0 + r < N_NODES) {
            float as = 0.f, ad = 0.f;
#pragma unroll
            for (int c = 0; c < 16; ++c) {
                float v = xs[r][hh * 16 + c];
                as = fmaf(v, a_src[hh * 16 + c], as);
                ad = fmaf(v, a_dst[hh * 16 + c], ad);
            }
            ssrc[(row0 + r) * 8 + hh] = as;
            sdst[(row0 + r) * 8 + hh] = ad;
        }
    }
    // ---- rank writes (atomic returns now long since landed) ----
#pragma unroll
    for (int i = 0; i < 4; ++i) {
        long long e = ebase + tid + i * 256;
        if (e < E) rank[e] = rnk[i];
    }
}

// block-local inclusive scan (256/block) + raw block sums
__global__ void scan1_kernel(const int* __restrict__ deg,
                             int* __restrict__ incl,
                             int* __restrict__ bsum)
{
    __shared__ int tmp[256];
    int i = blockIdx.x * 256 + threadIdx.x;
    int v = (i < N_NODES) ? deg[i] : 0;
    tmp[threadIdx.x] = v;
    __syncthreads();
    for (int o = 1; o < 256; o <<= 1) {
        int t = (threadIdx.x >= (unsigned)o) ? tmp[threadIdx.x - o] : 0;
        __syncthreads();
        tmp[threadIdx.x] += t;
        __syncthreads();
    }
    if (i < N_NODES) incl[i] = tmp[threadIdx.x];
    if (threadIdx.x == 255) bsum[blockIdx.x] = tmp[255];
}

// offsets[i+1] = incl[i] + prefix(bsum, block); each block reduces its own
// bsum prefix (<=391 ints) -- absorbs the old scan2 launch.
__global__ void scan3_kernel(const int* __restrict__ incl,
                             const int* __restrict__ bsum,
                             int* __restrict__ offsets)
{
    __shared__ int red[256];
    const int t = threadIdx.x;
    int s = 0;
    for (int i = t; i < blockIdx.x; i += 256) s += bsum[i];
    red[t] = s;
    __syncthreads();
    for (int o = 128; o > 0; o >>= 1) {
        if (t < o) red[t] += red[t + o];
        __syncthreads();
    }
    const int base = red[0];
    int i = blockIdx.x * 256 + t;
    if (i < N_NODES) offsets[i + 1] = incl[i] + base;
    if (i == 0) offsets[0] = 0;
}

// atomic-free scatter using precomputed rank
__global__ void scatter_kernel(const int* __restrict__ ei, int E,
                               const int* __restrict__ offsets,
                               const int* __restrict__ rank,
                               int* __restrict__ srcs)
{
    int e = blockIdx.x * blockDim.x + threadIdx.x;
    if (e >= E) return;
    int s = ei[e], d = ei[E + e];
    srcs[offsets[d] + rank[e]] = s;
}

// ---------------- layer 1 gather: one wave per dst node (fp8 h rows) --------
__global__ void gather1_kernel(const uint32* __restrict__ h8,   // N x 32 dwords
                               const float* __restrict__ ssrc,
                               const float* __restrict__ sdst,
                               const int* __restrict__ offsets,
                               const int* __restrict__ srcs,
                               const float* __restrict__ b1,
                               float* __restrict__ out)
{
    int d = (blockIdx.x * blockDim.x + threadIdx.x) >> 6;
    int lane = threadIdx.x & 63;
    if (d >= N_NODES) return;
    const int hw = lane & 7;            // head in weight phase
    const int half = lane >> 5;         // edge parity in accumulate phase
    const int u = lane & 31;            // dword in row: channels 4u..4u+3
    const int hc = u >> 2;              // head of my channels
    const float sd_w = sdst[d * H1 + hw];

    float acc0 = 0.f, acc1 = 0.f, acc2 = 0.f, acc3 = 0.f;
    float wsum = 0.f;

    // self-loop weight for my channel head
    float lgs = ssrc[d * H1 + hc] + sdst[d * H1 + hc];
    lgs = lgs >= 0.f ? lgs : NEG * lgs;
    const float ws_self = __expf(lgs);
    {   // only half 0 accumulates the self row (avoid double count)
        float m = (half == 0) ? ws_self : 0.f;
        uint32 p = h8[(size_t)d * 32 + u];
        v2f lo = __builtin_amdgcn_cvt_pk_f32_fp8((int)p, false);
        v2f hi = __builtin_amdgcn_cvt_pk_f32_fp8((int)p, true);
        acc0 = m * lo[0]; acc1 = m * lo[1];
        acc2 = m * hi[0]; acc3 = m * hi[1];
    }

    const int beg = offsets[d], end = offsets[d + 1];
    int base = beg;
    for (; base + 8 <= end; base += 8) {
        int s_l = srcs[base + (lane >> 3)];
        float lg = ssrc[s_l * H1 + hw] + sd_w;
        lg = lg >= 0.f ? lg : NEG * lg;
        float w_l = __expf(lg);
        wsum += w_l;
#pragma unroll
        for (int t = 0; t < 4; ++t) {
            int j = 2 * t + half;
            int s = __shfl(s_l, j << 3);
            float w = __shfl(w_l, (j << 3) | hc);
            uint32 p = h8[(size_t)s * 32 + u];
            v2f lo = __builtin_amdgcn_cvt_pk_f32_fp8((int)p, false);
            v2f hi = __builtin_amdgcn_cvt_pk_f32_fp8((int)p, true);
            acc0 = fmaf(w, lo[0], acc0);
            acc1 = fmaf(w, lo[1], acc1);
            acc2 = fmaf(w, hi[0], acc2);
            acc3 = fmaf(w, hi[1], acc3);
        }
    }
    int cnt = end - base;
    if (cnt > 0) {
        int s_l = 0; float w_l = 0.f;
        if ((lane >> 3) < cnt) {
            s_l = srcs[base + (lane >> 3)];
            float lg = ssrc[s_l * H1 + hw] + sd_w;
            lg = lg >= 0.f ? lg : NEG * lg;
            w_l = __expf(lg);
        }
        wsum += w_l;
        int steps = (cnt + 1) >> 1;
        for (int t = 0; t < steps; ++t) {
            int j = 2 * t + half;        // j may equal cnt (odd tail): w=0 there
            int s = __shfl(s_l, j << 3);
            float w = __shfl(w_l, (j << 3) | hc);
            uint32 p = h8[(size_t)s * 32 + u];
            v2f lo = __builtin_amdgcn_cvt_pk_f32_fp8((int)p, false);
            v2f hi = __builtin_amdgcn_cvt_pk_f32_fp8((int)p, true);
            acc0 = fmaf(w, lo[0], acc0);
            acc1 = fmaf(w, lo[1], acc1);
            acc2 = fmaf(w, hi[0], acc2);
            acc3 = fmaf(w, hi[1], acc3);
        }
    }
    // head-wise total: sum wsum over the 8 edge-slot groups (xor bits 3..5)
    wsum += __shfl_xor(wsum, 8);
    wsum += __shfl_xor(wsum, 16);
    wsum += __shfl_xor(wsum, 32);
    float ws = ws_self + __shfl(wsum, hc);
    // cross-half accumulator reduce
    acc0 += __shfl_xor(acc0, 32);
    acc1 += __shfl_xor(acc1, 32);
    acc2 += __shfl_xor(acc2, 32);
    acc3 += __shfl_xor(acc3, 32);
    if (half == 0) {
        float inv = 1.f / (ws + 1e-16f);
        float4 bb = ((const float4*)b1)[u];
        float4 r;
        r.x = fmaf(acc0, inv, bb.x); r.x = r.x > 0.f ? r.x : 0.f;
        r.y = fmaf(acc1, inv, bb.y); r.y = r.y > 0.f ? r.y : 0.f;
        r.z = fmaf(acc2, inv, bb.z); r.z = r.z > 0.f ? r.z : 0.f;
        r.w = fmaf(acc3, inv, bb.w); r.w = r.w > 0.f ? r.w : 0.f;
        ((float4*)(out + (size_t)d * D1))[u] = r;
    }
}

// ---------------- layer 2 GEMM + logits, fused ------------------------------
// 64 rows/block, thread = 2 rows (rr, rr+32) x 5 cols.
__global__ __launch_bounds__(256) void gemm2_kernel(
    const float* __restrict__ h, const float* __restrict__ W2,
    ushort16* __restrict__ h2b,
    const float* __restrict__ a_src, const float* __restrict__ a_dst,
    float* __restrict__ ssrc, float* __restrict__ sdst)
{
    __shared__ float w2s[40][132];
    __shared__ float hs[64][132];
    const int row0 = blockIdx.x * 64;
    const int tid = threadIdx.x;
#pragma unroll
    for (int i = 0; i < 20; ++i) {
        int idx = tid + i * 256;     // 0..5119
        int k = idx / 40, c = idx % 40;
        w2s[c][k] = W2[idx];
    }
#pragma unroll
    for (int i = 0; i < 8; ++i) {
        int idx = tid + i * 256;     // 0..2047
        int r = idx >> 5, c4 = idx & 31;
        float4 v = make_float4(0.f, 0.f, 0.f, 0.f);
        if (row0 + r < N_NODES)
            v = ((const float4*)h)[(size_t)(row0 + r) * 32 + c4];
        *(float4*)&hs[r][c4 * 4] = v;
    }
    __syncthreads();
    const int rr = tid >> 3;     // row pair (rr, rr+32)
    const int g  = tid & 7;      // cols 5g..5g+4
    float acc[2][5];
#pragma unroll
    for (int t = 0; t < 2; ++t)
#pragma unroll
        for (int j = 0; j < 5; ++j) acc[t][j] = 0.f;
    for (int k0 = 0; k0 < 128; k0 += 4) {
        float4 ha = *(const float4*)&hs[rr][k0];
        float4 hb = *(const float4*)&hs[rr + 32][k0];
#pragma unroll
        for (int j = 0; j < 5; ++j) {
            float4 wv = *(const float4*)&w2s[5 * g + j][k0];
            acc[0][j] = fmaf(ha.x, wv.x, acc[0][j]);
            acc[0][j] = fmaf(ha.y, wv.y, acc[0][j]);
            acc[0][j] = fmaf(ha.z, wv.z, acc[0][j]);
            acc[0][j] = fmaf(ha.w, wv.w, acc[0][j]);
            acc[1][j] = fmaf(hb.x, wv.x, acc[1][j]);
            acc[1][j] = fmaf(hb.y, wv.y, acc[1][j]);
            acc[1][j] = fmaf(hb.z, wv.z, acc[1][j]);
            acc[1][j] = fmaf(hb.w, wv.w, acc[1][j]);
        }
    }
#pragma unroll
    for (int t = 0; t < 2; ++t) {
        int row = row0 + rr + 32 * t;
        if (row < N_NODES) {
#pragma unroll
            for (int j = 0; j < 5; ++j)
                h2b[(size_t)row * 40 + 5 * g + j] = f2bf(acc[t][j]);
        }
    }
    __syncthreads();     // all reads of hs done
#pragma unroll
    for (int t = 0; t < 2; ++t)
#pragma unroll
        for (int j = 0; j < 5; ++j)
            hs[rr + 32 * t][5 * g + j] = acc[t][j];
    __syncthreads();
    if (tid < 64 && row0 + tid < N_NODES) {
        float as = 0.f, ad = 0.f;
#pragma unroll
        for (int c = 0; c < 40; ++c) {
            float v = hs[tid][c];
            as = fmaf(v, a_src[c], as);
            ad = fmaf(v, a_dst[c], ad);
        }
        ssrc[row0 + tid] = as;
        sdst[row0 + tid] = ad;
    }
}

// ---------------- layer 2 gather + log_softmax: one wave per node (bf16) ----
__global__ void gather2_kernel(const uint32* __restrict__ h2b,  // N x 20 uints
                               const float* __restrict__ ssrc,
                               const float* __restrict__ sdst,
                               const int* __restrict__ offsets,
                               const int* __restrict__ srcs,
                               const float* __restrict__ b2,
                               float* __restrict__ out)
{
    int d = (blockIdx.x * blockDim.x + threadIdx.x) >> 6;
    int lane = threadIdx.x & 63;
    if (d >= N_NODES) return;
    const float sd = sdst[d];
    const int g = lane / 20;              // group 0..2 (3 = idle tail lanes)
    const int c = lane - 20 * g;          // dword within row (channels 2c,2c+1)
    const bool act = lane < (NCLS / 2);   // lanes that own the output
    float acc0 = 0.f, acc1 = 0.f, ws = 0.f;

    // self-loop (group 0 only)
    {
        float lg = ssrc[d] + sd; lg = lg >= 0.f ? lg : NEG * lg;
        float w = __expf(lg);
        uint32 p = act ? h2b[(size_t)d * 20 + lane] : 0u;
        float m = act ? w : 0.f;
        acc0 = m * bf_lo(p); acc1 = m * bf_hi(p);
        ws = w;
    }
    const int beg = offsets[d], end = offsets[d + 1];
    for (int base = beg; base < end; base += 64) {
        int cnt = end - base; if (cnt > 64) cnt = 64;
        int s_l = 0; float w_l = 0.f;
        if (lane < cnt) {
            s_l = srcs[base + lane];
            float lg = ssrc[s_l] + sd; lg = lg >= 0.f ? lg : NEG * lg;
            w_l = __expf(lg);
        }
        float t = w_l;
#pragma unroll
        for (int o = 32; o > 0; o >>= 1) t += __shfl_xor(t, o);
        ws += t;
        for (int j = 0; j < cnt; j += 3) {
            int jj = j + g;
            int s = __shfl(s_l, jj & 63);
            float w = __shfl(w_l, jj & 63);
            if (g >= 3 || jj >= cnt) w = 0.f;
            uint32 p = h2b[(size_t)s * 20 + c];
            acc0 = fmaf(w, bf_lo(p), acc0);
            acc1 = fmaf(w, bf_hi(p), acc1);
        }
    }
    // cross-group reduce: groups live at lanes c, c+20, c+40
    float r00 = __shfl(acc0, lane + 20), r01 = __shfl(acc0, lane + 40);
    float r10 = __shfl(acc1, lane + 20), r11 = __shfl(acc1, lane + 40);
    float l0 = -INFINITY, l1 = -INFINITY;
    if (act) {
        acc0 += r00 + r01;
        acc1 += r10 + r11;
        float inv = 1.f / (ws + 1e-16f);
        l0 = fmaf(acc0, inv, b2[2 * lane]);
        l1 = fmaf(acc1, inv, b2[2 * lane + 1]);
    }
    float m = fmaxf(l0, l1);
#pragma unroll
    for (int o = 32; o > 0; o >>= 1) m = fmaxf(m, __shfl_xor(m, o));
    float ex = act ? (__expf(l0 - m) + __expf(l1 - m)) : 0.f;
#pragma unroll
    for (int o = 32; o > 0; o >>= 1) ex += __shfl_xor(ex, o);
    float lse = __logf(ex) + m;
    if (act) {
        float2 r; r.x = l0 - lse; r.y = l1 - lse;
        ((float2*)(out + (size_t)d * NCLS))[lane] = r;
    }
}

extern "C" void kernel_launch(void* const* d_in, const int* in_sizes, int n_in,
                              void* d_out, int out_size, void* d_ws, size_t ws_size,
                              hipStream_t stream)
{
    const float* x   = (const float*)d_in[0];
    const int*   ei  = (const int*)  d_in[1];
    const float* W1  = (const float*)d_in[2];
    const float* as1 = (const float*)d_in[3];
    const float* ad1 = (const float*)d_in[4];
    const float* b1  = (const float*)d_in[5];
    const float* W2  = (const float*)d_in[6];
    const float* as2 = (const float*)d_in[7];
    const float* ad2 = (const float*)d_in[8];
    const float* b2  = (const float*)d_in[9];
    float* out = (float*)d_out;
    const int E = in_sizes[1] / 2;

    float* ws = (float*)d_ws;
    size_t off = 0;
    uint32* h1f8 = (uint32*)(ws + off); off += (size_t)N_NODES * 32;  // fp8 N x 128
    float* h1r  = ws + off; off += (size_t)N_NODES * D1;
    float* ss1  = ws + off; off += (size_t)N_NODES * H1;
    float* sd1  = ws + off; off += (size_t)N_NODES * H1;
    uint32* h2b = (uint32*)(ws + off); off += (size_t)N_NODES * 20;   // bf16 N x 40
    float* ss2  = ws + off; off += N_NODES;
    float* sd2  = ws + off; off += N_NODES;
    int* ib = (int*)(ws + off);
    size_t ioff = 0;
    int* deg     = ib + ioff; ioff += N_NODES;      // must be zeroed
    int* incl    = ib + ioff; ioff += N_NODES;
    int* offsets = ib + ioff; ioff += N_NODES + 1;
    int* bsum    = ib + ioff; ioff += 512;
    int* rank    = ib + ioff; ioff += E;
    int* srcs    = ib + ioff; ioff += E;

    hipMemsetAsync(deg, 0, (size_t)N_NODES * sizeof(int), stream);

    const int nb = (N_NODES + 255) / 256;           // 391

    // fused layer-1 gemm(+logits) + CSR count (uniform blocks; NG*1024 >= E)
    gemm1_count_kernel<<<NG, 256, 0, stream>>>(x, W1, h1f8, as1, ad1,
                                               ss1, sd1, ei, E, deg, rank);
    // CSR finish (scan2 absorbed into scan3)
    scan1_kernel<<<nb, 256, 0, stream>>>(deg, incl, bsum);
    scan3_kernel<<<nb, 256, 0, stream>>>(incl, bsum, offsets);
    scatter_kernel<<<(E + 255) / 256, 256, 0, stream>>>(ei, E, offsets, rank, srcs);

    // layer 1 gather
    gather1_kernel<<<(N_NODES * 64 + 255) / 256, 256, 0, stream>>>(h1f8, ss1, sd1, offsets, srcs, b1, h1r);

    // layer 2 (gemm + logits fused)
    gemm2_kernel<<<(N_NODES + 63) / 64, 256, 0, stream>>>(h1r, W2, (ushort16*)h2b, as2, ad2, ss2, sd2);
    gather2_kernel<<<(N_NODES * 64 + 255) / 256, 256, 0, stream>>>(h2b, ss2, sd2, offsets, srcs, b2, out);
}

// Round 10
// 405.417 us; speedup vs baseline: 1.0088x; 1.0088x over previous
//
#include <hip/hip_runtime.h>
#include <math.h>

#define N_NODES 100000
#define F_IN    128
#define H1      8
#define C1      16
#define D1      128   // H1*C1
#define NCLS    40
#define NEG     0.2f

typedef unsigned int uint32;
typedef unsigned short ushort16;
typedef float v2f __attribute__((ext_vector_type(2)));

__device__ __forceinline__ ushort16 f2bf(float f) {
    unsigned int u = __float_as_uint(f);
    u += 0x7fffu + ((u >> 16) & 1u);          // round-to-nearest-even
    return (ushort16)(u >> 16);
}
__device__ __forceinline__ float bf_lo(uint32 p) { return __uint_as_float(p << 16); }
__device__ __forceinline__ float bf_hi(uint32 p) { return __uint_as_float(p & 0xffff0000u); }

#define NG 1563   // gemm blocks (64 rows each); each also counts 1024 edges

// ---------------- fused: layer-1 GEMM(+logits) + CSR-count, uniform blocks --
// Count slice moved to the END of the block: the GEMM front-end never waits
// on atomic returns (vmcnt FIFO ordering!), and each block's ~2us atomic tail
// overlaps other resident blocks' compute.
__global__ __launch_bounds__(256) void gemm1_count_kernel(
    const float* __restrict__ x, const float* __restrict__ W,
    uint32* __restrict__ h8,            // fp8 rows, N x 32 dwords
    const float* __restrict__ a_src, const float* __restrict__ a_dst,
    float* __restrict__ ssrc, float* __restrict__ sdst,
    const int* __restrict__ ei, int E,
    int* __restrict__ deg, int* __restrict__ rank)
{
    __shared__ float xs[64][132];       // x tile (fp32), later h1 tile
    __shared__ float wt[128][68];       // W chunk transposed: wt[col][k]
    const int bid = blockIdx.x;
    const int tid = threadIdx.x;

    const int row0 = bid * 64;
    // ---- load x tile (coalesced float4) ----
#pragma unroll
    for (int i = 0; i < 8; ++i) {
        int idx = tid + i * 256;      // 0..2047
        int r = idx >> 5, c4 = idx & 31;
        float4 v = make_float4(0.f, 0.f, 0.f, 0.f);
        if (row0 + r < N_NODES)
            v = ((const float4*)x)[(size_t)(row0 + r) * 32 + c4];
        *(float4*)&xs[r][c4 * 4] = v;
    }
    const int cg = tid & 15;
    const int rg = tid >> 4;
    float acc[4][8];
#pragma unroll
    for (int i = 0; i < 4; ++i)
#pragma unroll
        for (int j = 0; j < 8; ++j) acc[i][j] = 0.f;

    const int stc = tid & 127;        // staging: col
    const int sth = tid >> 7;         // staging: k-half (0..1)
#pragma unroll
    for (int chunk = 0; chunk < 2; ++chunk) {
        const int kbase = chunk * 64;
        __syncthreads();              // wt free / x tile ready
#pragma unroll
        for (int kk = 0; kk < 8; ++kk) {
            int k = sth * 32 + kk * 4;
            float4 v;
            v.x = W[(size_t)(kbase + k)     * 128 + stc];
            v.y = W[(size_t)(kbase + k + 1) * 128 + stc];
            v.z = W[(size_t)(kbase + k + 2) * 128 + stc];
            v.w = W[(size_t)(kbase + k + 3) * 128 + stc];
            *(float4*)&wt[stc][k] = v;
        }
        __syncthreads();
        for (int k0 = 0; k0 < 64; k0 += 4) {
            float4 wa[8];
#pragma unroll
            for (int j = 0; j < 8; ++j)
                wa[j] = *(const float4*)&wt[cg + 16 * j][k0];
#pragma unroll
            for (int i = 0; i < 4; ++i) {
                float4 hx = *(const float4*)&xs[rg + 16 * i][kbase + k0];
#pragma unroll
                for (int j = 0; j < 8; ++j) {
                    acc[i][j] = fmaf(hx.x, wa[j].x, acc[i][j]);
                    acc[i][j] = fmaf(hx.y, wa[j].y, acc[i][j]);
                    acc[i][j] = fmaf(hx.z, wa[j].z, acc[i][j]);
                    acc[i][j] = fmaf(hx.w, wa[j].w, acc[i][j]);
                }
            }
        }
    }
    __syncthreads();   // all reads of x tile done
    // ---- write h1 (fp32) back into xs ----
#pragma unroll
    for (int i = 0; i < 4; ++i)
#pragma unroll
        for (int j = 0; j < 8; ++j)
            xs[rg + 16 * i][cg + 16 * j] = acc[i][j];
    __syncthreads();
    // ---- fp8 pack: 64 rows x 16 uint2-groups, 4 tasks/thread ----
#pragma unroll
    for (int t = 0; t < 4; ++t) {
        int task = tid + t * 256;     // 0..1023
        int r = task >> 4, g = task & 15;
        if (row0 + r < N_NODES) {
            float4 a = *(const float4*)&xs[r][8 * g];
            float4 b = *(const float4*)&xs[r][8 * g + 4];
            int p0 = __builtin_amdgcn_cvt_pk_fp8_f32(a.x, a.y, 0, false);
            p0     = __builtin_amdgcn_cvt_pk_fp8_f32(a.z, a.w, p0, true);
            int p1 = __builtin_amdgcn_cvt_pk_fp8_f32(b.x, b.y, 0, false);
            p1     = __builtin_amdgcn_cvt_pk_fp8_f32(b.z, b.w, p1, true);
            uint2 pk; pk.x = (uint32)p0; pk.y = (uint32)p1;
            ((uint2*)h8)[(size_t)(row0 + r) * 16 + g] = pk;
        }
    }
    // ---- logits: 64 rows x 8 heads = 512 tasks, 2 per thread ----
#pragma unroll
    for (int t = 0; t < 2; ++t) {
        int task = tid + t * 256;
        int r = task >> 3, hh = task & 7;
        if (row0 + r < N_NODES) {
            float as = 0.f, ad = 0.f;
#pragma unroll
            for (int c = 0; c < 16; ++c) {
                float v = xs[r][hh * 16 + c];
                as = fmaf(v, a_src[hh * 16 + c], as);
                ad = fmaf(v, a_dst[hh * 16 + c], ad);
            }
            ssrc[(row0 + r) * 8 + hh] = as;
            sdst[(row0 + r) * 8 + hh] = ad;
        }
    }
    // ---- count slice LAST: ei load -> atomic -> rank store ----
    const long long ebase = (long long)bid * 1024;
#pragma unroll
    for (int i = 0; i < 4; ++i) {
        long long e = ebase + tid + i * 256;
        if (e < E) {
            int dst = ei[E + e];
            rank[e] = atomicAdd(&deg[dst], 1);
        }
    }
}

// block-local inclusive scan (256/block) + raw block sums
__global__ void scan1_kernel(const int* __restrict__ deg,
                             int* __restrict__ incl,
                             int* __restrict__ bsum)
{
    __shared__ int tmp[256];
    int i = blockIdx.x * 256 + threadIdx.x;
    int v = (i < N_NODES) ? deg[i] : 0;
    tmp[threadIdx.x] = v;
    __syncthreads();
    for (int o = 1; o < 256; o <<= 1) {
        int t = (threadIdx.x >= (unsigned)o) ? tmp[threadIdx.x - o] : 0;
        __syncthreads();
        tmp[threadIdx.x] += t;
        __syncthreads();
    }
    if (i < N_NODES) incl[i] = tmp[threadIdx.x];
    if (threadIdx.x == 255) bsum[blockIdx.x] = tmp[255];
}

// offsets[i+1] = incl[i] + prefix(bsum, block); each block reduces its own
// bsum prefix (<=391 ints) -- absorbs the old scan2 launch.
__global__ void scan3_kernel(const int* __restrict__ incl,
                             const int* __restrict__ bsum,
                             int* __restrict__ offsets)
{
    __shared__ int red[256];
    const int t = threadIdx.x;
    int s = 0;
    for (int i = t; i < blockIdx.x; i += 256) s += bsum[i];
    red[t] = s;
    __syncthreads();
    for (int o = 128; o > 0; o >>= 1) {
        if (t < o) red[t] += red[t + o];
        __syncthreads();
    }
    const int base = red[0];
    int i = blockIdx.x * 256 + t;
    if (i < N_NODES) offsets[i + 1] = incl[i] + base;
    if (i == 0) offsets[0] = 0;
}

// atomic-free scatter using precomputed rank
__global__ void scatter_kernel(const int* __restrict__ ei, int E,
                               const int* __restrict__ offsets,
                               const int* __restrict__ rank,
                               int* __restrict__ srcs)
{
    int e = blockIdx.x * blockDim.x + threadIdx.x;
    if (e >= E) return;
    int s = ei[e], d = ei[E + e];
    srcs[offsets[d] + rank[e]] = s;
}

// ---------------- layer 1 gather: one wave per dst node (fp8 h rows) --------
__global__ void gather1_kernel(const uint32* __restrict__ h8,   // N x 32 dwords
                               const float* __restrict__ ssrc,
                               const float* __restrict__ sdst,
                               const int* __restrict__ offsets,
                               const int* __restrict__ srcs,
                               const float* __restrict__ b1,
                               float* __restrict__ out)
{
    int d = (blockIdx.x * blockDim.x + threadIdx.x) >> 6;
    int lane = threadIdx.x & 63;
    if (d >= N_NODES) return;
    const int hw = lane & 7;            // head in weight phase
    const int half = lane >> 5;         // edge parity in accumulate phase
    const int u = lane & 31;            // dword in row: channels 4u..4u+3
    const int hc = u >> 2;              // head of my channels
    const float sd_w = sdst[d * H1 + hw];

    float acc0 = 0.f, acc1 = 0.f, acc2 = 0.f, acc3 = 0.f;
    float wsum = 0.f;

    // self-loop weight for my channel head
    float lgs = ssrc[d * H1 + hc] + sdst[d * H1 + hc];
    lgs = lgs >= 0.f ? lgs : NEG * lgs;
    const float ws_self = __expf(lgs);
    {   // only half 0 accumulates the self row (avoid double count)
        float m = (half == 0) ? ws_self : 0.f;
        uint32 p = h8[(size_t)d * 32 + u];
        v2f lo = __builtin_amdgcn_cvt_pk_f32_fp8((int)p, false);
        v2f hi = __builtin_amdgcn_cvt_pk_f32_fp8((int)p, true);
        acc0 = m * lo[0]; acc1 = m * lo[1];
        acc2 = m * hi[0]; acc3 = m * hi[1];
    }

    const int beg = offsets[d], end = offsets[d + 1];
    int base = beg;
    for (; base + 8 <= end; base += 8) {
        int s_l = srcs[base + (lane >> 3)];
        float lg = ssrc[s_l * H1 + hw] + sd_w;
        lg = lg >= 0.f ? lg : NEG * lg;
        float w_l = __expf(lg);
        wsum += w_l;
#pragma unroll
        for (int t = 0; t < 4; ++t) {
            int j = 2 * t + half;
            int s = __shfl(s_l, j << 3);
            float w = __shfl(w_l, (j << 3) | hc);
            uint32 p = h8[(size_t)s * 32 + u];
            v2f lo = __builtin_amdgcn_cvt_pk_f32_fp8((int)p, false);
            v2f hi = __builtin_amdgcn_cvt_pk_f32_fp8((int)p, true);
            acc0 = fmaf(w, lo[0], acc0);
            acc1 = fmaf(w, lo[1], acc1);
            acc2 = fmaf(w, hi[0], acc2);
            acc3 = fmaf(w, hi[1], acc3);
        }
    }
    int cnt = end - base;
    if (cnt > 0) {
        int s_l = 0; float w_l = 0.f;
        if ((lane >> 3) < cnt) {
            s_l = srcs[base + (lane >> 3)];
            float lg = ssrc[s_l * H1 + hw] + sd_w;
            lg = lg >= 0.f ? lg : NEG * lg;
            w_l = __expf(lg);
        }
        wsum += w_l;
        int steps = (cnt + 1) >> 1;
        for (int t = 0; t < steps; ++t) {
            int j = 2 * t + half;        // j may equal cnt (odd tail): w=0 there
            int s = __shfl(s_l, j << 3);
            float w = __shfl(w_l, (j << 3) | hc);
            uint32 p = h8[(size_t)s * 32 + u];
            v2f lo = __builtin_amdgcn_cvt_pk_f32_fp8((int)p, false);
            v2f hi = __builtin_amdgcn_cvt_pk_f32_fp8((int)p, true);
            acc0 = fmaf(w, lo[0], acc0);
            acc1 = fmaf(w, lo[1], acc1);
            acc2 = fmaf(w, hi[0], acc2);
            acc3 = fmaf(w, hi[1], acc3);
        }
    }
    // head-wise total: sum wsum over the 8 edge-slot groups (xor bits 3..5)
    wsum += __shfl_xor(wsum, 8);
    wsum += __shfl_xor(wsum, 16);
    wsum += __shfl_xor(wsum, 32);
    float ws = ws_self + __shfl(wsum, hc);
    // cross-half accumulator reduce
    acc0 += __shfl_xor(acc0, 32);
    acc1 += __shfl_xor(acc1, 32);
    acc2 += __shfl_xor(acc2, 32);
    acc3 += __shfl_xor(acc3, 32);
    if (half == 0) {
        float inv = 1.f / (ws + 1e-16f);
        float4 bb = ((const float4*)b1)[u];
        float4 r;
        r.x = fmaf(acc0, inv, bb.x); r.x = r.x > 0.f ? r.x : 0.f;
        r.y = fmaf(acc1, inv, bb.y); r.y = r.y > 0.f ? r.y : 0.f;
        r.z = fmaf(acc2, inv, bb.z); r.z = r.z > 0.f ? r.z : 0.f;
        r.w = fmaf(acc3, inv, bb.w); r.w = r.w > 0.f ? r.w : 0.f;
        ((float4*)(out + (size_t)d * D1))[u] = r;
    }
}

// ---------------- layer 2 GEMM + logits, fused ------------------------------
// 64 rows/block, thread = 2 rows (rr, rr+32) x 5 cols.
__global__ __launch_bounds__(256) void gemm2_kernel(
    const float* __restrict__ h, const float* __restrict__ W2,
    ushort16* __restrict__ h2b,
    const float* __restrict__ a_src, const float* __restrict__ a_dst,
    float* __restrict__ ssrc, float* __restrict__ sdst)
{
    __shared__ float w2s[40][132];
    __shared__ float hs[64][132];
    const int row0 = blockIdx.x * 64;
    const int tid = threadIdx.x;
#pragma unroll
    for (int i = 0; i < 20; ++i) {
        int idx = tid + i * 256;     // 0..5119
        int k = idx / 40, c = idx % 40;
        w2s[c][k] = W2[idx];
    }
#pragma unroll
    for (int i = 0; i < 8; ++i) {
        int idx = tid + i * 256;     // 0..2047
        int r = idx >> 5, c4 = idx & 31;
        float4 v = make_float4(0.f, 0.f, 0.f, 0.f);
        if (row0 + r < N_NODES)
            v = ((const float4*)h)[(size_t)(row0 + r) * 32 + c4];
        *(float4*)&hs[r][c4 * 4] = v;
    }
    __syncthreads();
    const int rr = tid >> 3;     // row pair (rr, rr+32)
    const int g  = tid & 7;      // cols 5g..5g+4
    float acc[2][5];
#pragma unroll
    for (int t = 0; t < 2; ++t)
#pragma unroll
        for (int j = 0; j < 5; ++j) acc[t][j] = 0.f;
    for (int k0 = 0; k0 < 128; k0 += 4) {
        float4 ha = *(const float4*)&hs[rr][k0];
        float4 hb = *(const float4*)&hs[rr + 32][k0];
#pragma unroll
        for (int j = 0; j < 5; ++j) {
            float4 wv = *(const float4*)&w2s[5 * g + j][k0];
            acc[0][j] = fmaf(ha.x, wv.x, acc[0][j]);
            acc[0][j] = fmaf(ha.y, wv.y, acc[0][j]);
            acc[0][j] = fmaf(ha.z, wv.z, acc[0][j]);
            acc[0][j] = fmaf(ha.w, wv.w, acc[0][j]);
            acc[1][j] = fmaf(hb.x, wv.x, acc[1][j]);
            acc[1][j] = fmaf(hb.y, wv.y, acc[1][j]);
            acc[1][j] = fmaf(hb.z, wv.z, acc[1][j]);
            acc[1][j] = fmaf(hb.w, wv.w, acc[1][j]);
        }
    }
#pragma unroll
    for (int t = 0; t < 2; ++t) {
        int row = row0 + rr + 32 * t;
        if (row < N_NODES) {
#pragma unroll
            for (int j = 0; j < 5; ++j)
                h2b[(size_t)row * 40 + 5 * g + j] = f2bf(acc[t][j]);
        }
    }
    __syncthreads();     // all reads of hs done
#pragma unroll
    for (int t = 0; t < 2; ++t)
#pragma unroll
        for (int j = 0; j < 5; ++j)
            hs[rr + 32 * t][5 * g + j] = acc[t][j];
    __syncthreads();
    if (tid < 64 && row0 + tid < N_NODES) {
        float as = 0.f, ad = 0.f;
#pragma unroll
        for (int c = 0; c < 40; ++c) {
            float v = hs[tid][c];
            as = fmaf(v, a_src[c], as);
            ad = fmaf(v, a_dst[c], ad);
        }
        ssrc[row0 + tid] = as;
        sdst[row0 + tid] = ad;
    }
}

// ---------------- layer 2 gather + log_softmax: one wave per node (bf16) ----
__global__ void gather2_kernel(const uint32* __restrict__ h2b,  // N x 20 uints
                               const float* __restrict__ ssrc,
                               const float* __restrict__ sdst,
                               const int* __restrict__ offsets,
                               const int* __restrict__ srcs,
                               const float* __restrict__ b2,
                               float* __restrict__ out)
{
    int d = (blockIdx.x * blockDim.x + threadIdx.x) >> 6;
    int lane = threadIdx.x & 63;
    if (d >= N_NODES) return;
    const float sd = sdst[d];
    const int g = lane / 20;              // group 0..2 (3 = idle tail lanes)
    const int c = lane - 20 * g;          // dword within row (channels 2c,2c+1)
    const bool act = lane < (NCLS / 2);   // lanes that own the output
    float acc0 = 0.f, acc1 = 0.f, ws = 0.f;

    // self-loop (group 0 only)
    {
        float lg = ssrc[d] + sd; lg = lg >= 0.f ? lg : NEG * lg;
        float w = __expf(lg);
        uint32 p = act ? h2b[(size_t)d * 20 + lane] : 0u;
        float m = act ? w : 0.f;
        acc0 = m * bf_lo(p); acc1 = m * bf_hi(p);
        ws = w;
    }
    const int beg = offsets[d], end = offsets[d + 1];
    for (int base = beg; base < end; base += 64) {
        int cnt = end - base; if (cnt > 64) cnt = 64;
        int s_l = 0; float w_l = 0.f;
        if (lane < cnt) {
            s_l = srcs[base + lane];
            float lg = ssrc[s_l] + sd; lg = lg >= 0.f ? lg : NEG * lg;
            w_l = __expf(lg);
        }
        float t = w_l;
#pragma unroll
        for (int o = 32; o > 0; o >>= 1) t += __shfl_xor(t, o);
        ws += t;
        for (int j = 0; j < cnt; j += 3) {
            int jj = j + g;
            int s = __shfl(s_l, jj & 63);
            float w = __shfl(w_l, jj & 63);
            if (g >= 3 || jj >= cnt) w = 0.f;
            uint32 p = h2b[(size_t)s * 20 + c];
            acc0 = fmaf(w, bf_lo(p), acc0);
            acc1 = fmaf(w, bf_hi(p), acc1);
        }
    }
    // cross-group reduce: groups live at lanes c, c+20, c+40
    float r00 = __shfl(acc0, lane + 20), r01 = __shfl(acc0, lane + 40);
    float r10 = __shfl(acc1, lane + 20), r11 = __shfl(acc1, lane + 40);
    float l0 = -INFINITY, l1 = -INFINITY;
    if (act) {
        acc0 += r00 + r01;
        acc1 += r10 + r11;
        float inv = 1.f / (ws + 1e-16f);
        l0 = fmaf(acc0, inv, b2[2 * lane]);
        l1 = fmaf(acc1, inv, b2[2 * lane + 1]);
    }
    float m = fmaxf(l0, l1);
#pragma unroll
    for (int o = 32; o > 0; o >>= 1) m = fmaxf(m, __shfl_xor(m, o));
    float ex = act ? (__expf(l0 - m) + __expf(l1 - m)) : 0.f;
#pragma unroll
    for (int o = 32; o > 0; o >>= 1) ex += __shfl_xor(ex, o);
    float lse = __logf(ex) + m;
    if (act) {
        float2 r; r.x = l0 - lse; r.y = l1 - lse;
        ((float2*)(out + (size_t)d * NCLS))[lane] = r;
    }
}

extern "C" void kernel_launch(void* const* d_in, const int* in_sizes, int n_in,
                              void* d_out, int out_size, void* d_ws, size_t ws_size,
                              hipStream_t stream)
{
    const float* x   = (const float*)d_in[0];
    const int*   ei  = (const int*)  d_in[1];
    const float* W1  = (const float*)d_in[2];
    const float* as1 = (const float*)d_in[3];
    const float* ad1 = (const float*)d_in[4];
    const float* b1  = (const float*)d_in[5];
    const float* W2  = (const float*)d_in[6];
    const float* as2 = (const float*)d_in[7];
    const float* ad2 = (const float*)d_in[8];
    const float* b2  = (const float*)d_in[9];
    float* out = (float*)d_out;
    const int E = in_sizes[1] / 2;

    float* ws = (float*)d_ws;
    size_t off = 0;
    uint32* h1f8 = (uint32*)(ws + off); off += (size_t)N_NODES * 32;  // fp8 N x 128
    float* h1r  = ws + off; off += (size_t)N_NODES * D1;
    float* ss1  = ws + off; off += (size_t)N_NODES * H1;
    float* sd1  = ws + off; off += (size_t)N_NODES * H1;
    uint32* h2b = (uint32*)(ws + off); off += (size_t)N_NODES * 20;   // bf16 N x 40
    float* ss2  = ws + off; off += N_NODES;
    float* sd2  = ws + off; off += N_NODES;
    int* ib = (int*)(ws + off);
    size_t ioff = 0;
    int* deg     = ib + ioff; ioff += N_NODES;      // must be zeroed
    int* incl    = ib + ioff; ioff += N_NODES;
    int* offsets = ib + ioff; ioff += N_NODES + 1;
    int* bsum    = ib + ioff; ioff += 512;
    int* rank    = ib + ioff; ioff += E;
    int* srcs    = ib + ioff; ioff += E;

    hipMemsetAsync(deg, 0, (size_t)N_NODES * sizeof(int), stream);

    const int nb = (N_NODES + 255) / 256;           // 391

    // fused layer-1 gemm(+logits) + CSR count (uniform blocks; NG*1024 >= E)
    gemm1_count_kernel<<<NG, 256, 0, stream>>>(x, W1, h1f8, as1, ad1,
                                               ss1, sd1, ei, E, deg, rank);
    // CSR finish (scan2 absorbed into scan3)
    scan1_kernel<<<nb, 256, 0, stream>>>(deg, incl, bsum);
    scan3_kernel<<<nb, 256, 0, stream>>>(incl, bsum, offsets);
    scatter_kernel<<<(E + 255) / 256, 256, 0, stream>>>(ei, E, offsets, rank, srcs);

    // layer 1 gather
    gather1_kernel<<<(N_NODES * 64 + 255) / 256, 256, 0, stream>>>(h1f8, ss1, sd1, offsets, srcs, b1, h1r);

    // layer 2 (gemm + logits fused)
    gemm2_kernel<<<(N_NODES + 63) / 64, 256, 0, stream>>>(h1r, W2, (ushort16*)h2b, as2, ad2, ss2, sd2);
    gather2_kernel<<<(N_NODES * 64 + 255) / 256, 256, 0, stream>>>(h2b, ss2, sd2, offsets, srcs, b2, out);
}

// Round 11
// 399.440 us; speedup vs baseline: 1.0239x; 1.0150x over previous
//
#include <hip/hip_runtime.h>
#include <math.h>

#define N_NODES 100000
#define F_IN    128
#define H1      8
#define C1      16
#define D1      128   // H1*C1
#define NCLS    40
#define NEG     0.2f

typedef unsigned int uint32;
typedef unsigned short ushort16;
typedef float v2f __attribute__((ext_vector_type(2)));

__device__ __forceinline__ ushort16 f2bf(float f) {
    unsigned int u = __float_as_uint(f);
    u += 0x7fffu + ((u >> 16) & 1u);          // round-to-nearest-even
    return (ushort16)(u >> 16);
}
__device__ __forceinline__ float bf_lo(uint32 p) { return __uint_as_float(p << 16); }
__device__ __forceinline__ float bf_hi(uint32 p) { return __uint_as_float(p & 0xffff0000u); }

#define NG 1563   // gemm blocks (64 rows each); each also counts 1024 edges

// ---------------- fused: layer-1 GEMM(+logits) + CSR-count, uniform blocks --
// W staged in LDS as bf16 (18.4 KB; stride 72 shorts -> 2-way bank alias max,
// free). Total LDS 52.2 KB -> 3 blocks/CU (was 2): atomic tails now overlap
// other blocks' compute, and K-loop LDS reads drop to 16 b128 / 256 FMAs.
__global__ __launch_bounds__(256) void gemm1_count_kernel(
    const float* __restrict__ x, const float* __restrict__ W,
    uint32* __restrict__ h8,            // fp8 rows, N x 32 dwords
    const float* __restrict__ a_src, const float* __restrict__ a_dst,
    float* __restrict__ ssrc, float* __restrict__ sdst,
    const int* __restrict__ ei, int E,
    int* __restrict__ deg, int* __restrict__ rank)
{
    __shared__ float xs[64][132];          // x tile (fp32), later h1 tile
    __shared__ ushort16 wt[128][72];       // W chunk transposed, bf16: wt[col][k]
    const int bid = blockIdx.x;
    const int tid = threadIdx.x;

    const int row0 = bid * 64;
    // ---- load x tile (coalesced float4) ----
#pragma unroll
    for (int i = 0; i < 8; ++i) {
        int idx = tid + i * 256;      // 0..2047
        int r = idx >> 5, c4 = idx & 31;
        float4 v = make_float4(0.f, 0.f, 0.f, 0.f);
        if (row0 + r < N_NODES)
            v = ((const float4*)x)[(size_t)(row0 + r) * 32 + c4];
        *(float4*)&xs[r][c4 * 4] = v;
    }
    const int cg = tid & 15;
    const int rg = tid >> 4;
    float acc[4][8];
#pragma unroll
    for (int i = 0; i < 4; ++i)
#pragma unroll
        for (int j = 0; j < 8; ++j) acc[i][j] = 0.f;

    const int stc = tid & 127;        // staging: col
    const int sth = tid >> 7;         // staging: k-half (0..1)
#pragma unroll
    for (int chunk = 0; chunk < 2; ++chunk) {
        const int kbase = chunk * 64;
        __syncthreads();              // wt free / x tile ready
        // ---- stage W[kbase..kbase+63][*] transposed into wt (bf16) ----
#pragma unroll
        for (int kk = 0; kk < 8; ++kk) {
            int k = sth * 32 + kk * 4;
            float4 v;
            v.x = W[(size_t)(kbase + k)     * 128 + stc];
            v.y = W[(size_t)(kbase + k + 1) * 128 + stc];
            v.z = W[(size_t)(kbase + k + 2) * 128 + stc];
            v.w = W[(size_t)(kbase + k + 3) * 128 + stc];
            uint2 p;
            p.x = (uint32)f2bf(v.x) | ((uint32)f2bf(v.y) << 16);
            p.y = (uint32)f2bf(v.z) | ((uint32)f2bf(v.w) << 16);
            *(uint2*)&wt[stc][k] = p;
        }
        __syncthreads();
        // ---- K-loop: 8 k-steps per iter (one b128 per col) ----
        for (int k0 = 0; k0 < 64; k0 += 8) {
            float4 ha[4], hb[4];
#pragma unroll
            for (int i = 0; i < 4; ++i) {
                ha[i] = *(const float4*)&xs[rg + 16 * i][kbase + k0];
                hb[i] = *(const float4*)&xs[rg + 16 * i][kbase + k0 + 4];
            }
#pragma unroll
            for (int j = 0; j < 8; ++j) {
                uint4 wu = *(const uint4*)&wt[cg + 16 * j][k0];
                float w0 = bf_lo(wu.x), w1 = bf_hi(wu.x);
                float w2 = bf_lo(wu.y), w3 = bf_hi(wu.y);
                float w4 = bf_lo(wu.z), w5 = bf_hi(wu.z);
                float w6 = bf_lo(wu.w), w7 = bf_hi(wu.w);
#pragma unroll
                for (int i = 0; i < 4; ++i) {
                    float a = acc[i][j];
                    a = fmaf(ha[i].x, w0, a);
                    a = fmaf(ha[i].y, w1, a);
                    a = fmaf(ha[i].z, w2, a);
                    a = fmaf(ha[i].w, w3, a);
                    a = fmaf(hb[i].x, w4, a);
                    a = fmaf(hb[i].y, w5, a);
                    a = fmaf(hb[i].z, w6, a);
                    a = fmaf(hb[i].w, w7, a);
                    acc[i][j] = a;
                }
            }
        }
    }
    __syncthreads();   // all reads of x tile done
    // ---- write h1 (fp32) back into xs ----
#pragma unroll
    for (int i = 0; i < 4; ++i)
#pragma unroll
        for (int j = 0; j < 8; ++j)
            xs[rg + 16 * i][cg + 16 * j] = acc[i][j];
    __syncthreads();
    // ---- fp8 pack: 64 rows x 16 uint2-groups, 4 tasks/thread ----
#pragma unroll
    for (int t = 0; t < 4; ++t) {
        int task = tid + t * 256;     // 0..1023
        int r = task >> 4, g = task & 15;
        if (row0 + r < N_NODES) {
            float4 a = *(const float4*)&xs[r][8 * g];
            float4 b = *(const float4*)&xs[r][8 * g + 4];
            int p0 = __builtin_amdgcn_cvt_pk_fp8_f32(a.x, a.y, 0, false);
            p0     = __builtin_amdgcn_cvt_pk_fp8_f32(a.z, a.w, p0, true);
            int p1 = __builtin_amdgcn_cvt_pk_fp8_f32(b.x, b.y, 0, false);
            p1     = __builtin_amdgcn_cvt_pk_fp8_f32(b.z, b.w, p1, true);
            uint2 pk; pk.x = (uint32)p0; pk.y = (uint32)p1;
            ((uint2*)h8)[(size_t)(row0 + r) * 16 + g] = pk;
        }
    }
    // ---- logits: 64 rows x 8 heads = 512 tasks, 2 per thread ----
#pragma unroll
    for (int t = 0; t < 2; ++t) {
        int task = tid + t * 256;
        int r = task >> 3, hh = task & 7;
        if (row0 + r < N_NODES) {
            float as = 0.f, ad = 0.f;
#pragma unroll
            for (int c = 0; c < 16; ++c) {
                float v = xs[r][hh * 16 + c];
                as = fmaf(v, a_src[hh * 16 + c], as);
                ad = fmaf(v, a_dst[hh * 16 + c], ad);
            }
            ssrc[(row0 + r) * 8 + hh] = as;
            sdst[(row0 + r) * 8 + hh] = ad;
        }
    }
    // ---- count slice LAST: ei load -> atomic -> rank store ----
    const long long ebase = (long long)bid * 1024;
#pragma unroll
    for (int i = 0; i < 4; ++i) {
        long long e = ebase + tid + i * 256;
        if (e < E) {
            int dst = ei[E + e];
            rank[e] = atomicAdd(&deg[dst], 1);
        }
    }
}

// block-local inclusive scan (256/block) + raw block sums
__global__ void scan1_kernel(const int* __restrict__ deg,
                             int* __restrict__ incl,
                             int* __restrict__ bsum)
{
    __shared__ int tmp[256];
    int i = blockIdx.x * 256 + threadIdx.x;
    int v = (i < N_NODES) ? deg[i] : 0;
    tmp[threadIdx.x] = v;
    __syncthreads();
    for (int o = 1; o < 256; o <<= 1) {
        int t = (threadIdx.x >= (unsigned)o) ? tmp[threadIdx.x - o] : 0;
        __syncthreads();
        tmp[threadIdx.x] += t;
        __syncthreads();
    }
    if (i < N_NODES) incl[i] = tmp[threadIdx.x];
    if (threadIdx.x == 255) bsum[blockIdx.x] = tmp[255];
}

// offsets[i+1] = incl[i] + prefix(bsum, block); absorbs old scan2 launch.
__global__ void scan3_kernel(const int* __restrict__ incl,
                             const int* __restrict__ bsum,
                             int* __restrict__ offsets)
{
    __shared__ int red[256];
    const int t = threadIdx.x;
    int s = 0;
    for (int i = t; i < blockIdx.x; i += 256) s += bsum[i];
    red[t] = s;
    __syncthreads();
    for (int o = 128; o > 0; o >>= 1) {
        if (t < o) red[t] += red[t + o];
        __syncthreads();
    }
    const int base = red[0];
    int i = blockIdx.x * 256 + t;
    if (i < N_NODES) offsets[i + 1] = incl[i] + base;
    if (i == 0) offsets[0] = 0;
}

// atomic-free scatter using precomputed rank
__global__ void scatter_kernel(const int* __restrict__ ei, int E,
                               const int* __restrict__ offsets,
                               const int* __restrict__ rank,
                               int* __restrict__ srcs)
{
    int e = blockIdx.x * blockDim.x + threadIdx.x;
    if (e >= E) return;
    int s = ei[e], d = ei[E + e];
    srcs[offsets[d] + rank[e]] = s;
}

// ---------------- layer 1 gather: one wave per dst node (fp8 h rows) --------
__global__ void gather1_kernel(const uint32* __restrict__ h8,   // N x 32 dwords
                               const float* __restrict__ ssrc,
                               const float* __restrict__ sdst,
                               const int* __restrict__ offsets,
                               const int* __restrict__ srcs,
                               const float* __restrict__ b1,
                               float* __restrict__ out)
{
    int d = (blockIdx.x * blockDim.x + threadIdx.x) >> 6;
    int lane = threadIdx.x & 63;
    if (d >= N_NODES) return;
    const int hw = lane & 7;            // head in weight phase
    const int half = lane >> 5;         // edge parity in accumulate phase
    const int u = lane & 31;            // dword in row: channels 4u..4u+3
    const int hc = u >> 2;              // head of my channels
    const float sd_w = sdst[d * H1 + hw];

    float acc0 = 0.f, acc1 = 0.f, acc2 = 0.f, acc3 = 0.f;
    float wsum = 0.f;

    // self-loop weight for my channel head
    float lgs = ssrc[d * H1 + hc] + sdst[d * H1 + hc];
    lgs = lgs >= 0.f ? lgs : NEG * lgs;
    const float ws_self = __expf(lgs);
    {   // only half 0 accumulates the self row (avoid double count)
        float m = (half == 0) ? ws_self : 0.f;
        uint32 p = h8[(size_t)d * 32 + u];
        v2f lo = __builtin_amdgcn_cvt_pk_f32_fp8((int)p, false);
        v2f hi = __builtin_amdgcn_cvt_pk_f32_fp8((int)p, true);
        acc0 = m * lo[0]; acc1 = m * lo[1];
        acc2 = m * hi[0]; acc3 = m * hi[1];
    }

    const int beg = offsets[d], end = offsets[d + 1];
    int base = beg;
    for (; base + 8 <= end; base += 8) {
        int s_l = srcs[base + (lane >> 3)];
        float lg = ssrc[s_l * H1 + hw] + sd_w;
        lg = lg >= 0.f ? lg : NEG * lg;
        float w_l = __expf(lg);
        wsum += w_l;
#pragma unroll
        for (int t = 0; t < 4; ++t) {
            int j = 2 * t + half;
            int s = __shfl(s_l, j << 3);
            float w = __shfl(w_l, (j << 3) | hc);
            uint32 p = h8[(size_t)s * 32 + u];
            v2f lo = __builtin_amdgcn_cvt_pk_f32_fp8((int)p, false);
            v2f hi = __builtin_amdgcn_cvt_pk_f32_fp8((int)p, true);
            acc0 = fmaf(w, lo[0], acc0);
            acc1 = fmaf(w, lo[1], acc1);
            acc2 = fmaf(w, hi[0], acc2);
            acc3 = fmaf(w, hi[1], acc3);
        }
    }
    int cnt = end - base;
    if (cnt > 0) {
        int s_l = 0; float w_l = 0.f;
        if ((lane >> 3) < cnt) {
            s_l = srcs[base + (lane >> 3)];
            float lg = ssrc[s_l * H1 + hw] + sd_w;
            lg = lg >= 0.f ? lg : NEG * lg;
            w_l = __expf(lg);
        }
        wsum += w_l;
        int steps = (cnt + 1) >> 1;
        for (int t = 0; t < steps; ++t) {
            int j = 2 * t + half;        // j may equal cnt (odd tail): w=0 there
            int s = __shfl(s_l, j << 3);
            float w = __shfl(w_l, (j << 3) | hc);
            uint32 p = h8[(size_t)s * 32 + u];
            v2f lo = __builtin_amdgcn_cvt_pk_f32_fp8((int)p, false);
            v2f hi = __builtin_amdgcn_cvt_pk_f32_fp8((int)p, true);
            acc0 = fmaf(w, lo[0], acc0);
            acc1 = fmaf(w, lo[1], acc1);
            acc2 = fmaf(w, hi[0], acc2);
            acc3 = fmaf(w, hi[1], acc3);
        }
    }
    // head-wise total: sum wsum over the 8 edge-slot groups (xor bits 3..5)
    wsum += __shfl_xor(wsum, 8);
    wsum += __shfl_xor(wsum, 16);
    wsum += __shfl_xor(wsum, 32);
    float ws = ws_self + __shfl(wsum, hc);
    // cross-half accumulator reduce
    acc0 += __shfl_xor(acc0, 32);
    acc1 += __shfl_xor(acc1, 32);
    acc2 += __shfl_xor(acc2, 32);
    acc3 += __shfl_xor(acc3, 32);
    if (half == 0) {
        float inv = 1.f / (ws + 1e-16f);
        float4 bb = ((const float4*)b1)[u];
        float4 r;
        r.x = fmaf(acc0, inv, bb.x); r.x = r.x > 0.f ? r.x : 0.f;
        r.y = fmaf(acc1, inv, bb.y); r.y = r.y > 0.f ? r.y : 0.f;
        r.z = fmaf(acc2, inv, bb.z); r.z = r.z > 0.f ? r.z : 0.f;
        r.w = fmaf(acc3, inv, bb.w); r.w = r.w > 0.f ? r.w : 0.f;
        ((float4*)(out + (size_t)d * D1))[u] = r;
    }
}

// ---------------- layer 2 GEMM + logits, fused ------------------------------
// 64 rows/block, thread = 2 rows (rr, rr+32) x 5 cols.
__global__ __launch_bounds__(256) void gemm2_kernel(
    const float* __restrict__ h, const float* __restrict__ W2,
    ushort16* __restrict__ h2b,
    const float* __restrict__ a_src, const float* __restrict__ a_dst,
    float* __restrict__ ssrc, float* __restrict__ sdst)
{
    __shared__ float w2s[40][132];
    __shared__ float hs[64][132];
    const int row0 = blockIdx.x * 64;
    const int tid = threadIdx.x;
#pragma unroll
    for (int i = 0; i < 20; ++i) {
        int idx = tid + i * 256;     // 0..5119
        int k = idx / 40, c = idx % 40;
        w2s[c][k] = W2[idx];
    }
#pragma unroll
    for (int i = 0; i < 8; ++i) {
        int idx = tid + i * 256;     // 0..2047
        int r = idx >> 5, c4 = idx & 31;
        float4 v = make_float4(0.f, 0.f, 0.f, 0.f);
        if (row0 + r < N_NODES)
            v = ((const float4*)h)[(size_t)(row0 + r) * 32 + c4];
        *(float4*)&hs[r][c4 * 4] = v;
    }
    __syncthreads();
    const int rr = tid >> 3;     // row pair (rr, rr+32)
    const int g  = tid & 7;      // cols 5g..5g+4
    float acc[2][5];
#pragma unroll
    for (int t = 0; t < 2; ++t)
#pragma unroll
        for (int j = 0; j < 5; ++j) acc[t][j] = 0.f;
    for (int k0 = 0; k0 < 128; k0 += 4) {
        float4 ha = *(const float4*)&hs[rr][k0];
        float4 hb = *(const float4*)&hs[rr + 32][k0];
#pragma unroll
        for (int j = 0; j < 5; ++j) {
            float4 wv = *(const float4*)&w2s[5 * g + j][k0];
            acc[0][j] = fmaf(ha.x, wv.x, acc[0][j]);
            acc[0][j] = fmaf(ha.y, wv.y, acc[0][j]);
            acc[0][j] = fmaf(ha.z, wv.z, acc[0][j]);
            acc[0][j] = fmaf(ha.w, wv.w, acc[0][j]);
            acc[1][j] = fmaf(hb.x, wv.x, acc[1][j]);
            acc[1][j] = fmaf(hb.y, wv.y, acc[1][j]);
            acc[1][j] = fmaf(hb.z, wv.z, acc[1][j]);
            acc[1][j] = fmaf(hb.w, wv.w, acc[1][j]);
        }
    }
#pragma unroll
    for (int t = 0; t < 2; ++t) {
        int row = row0 + rr + 32 * t;
        if (row < N_NODES) {
#pragma unroll
            for (int j = 0; j < 5; ++j)
                h2b[(size_t)row * 40 + 5 * g + j] = f2bf(acc[t][j]);
        }
    }
    __syncthreads();     // all reads of hs done
#pragma unroll
    for (int t = 0; t < 2; ++t)
#pragma unroll
        for (int j = 0; j < 5; ++j)
            hs[rr + 32 * t][5 * g + j] = acc[t][j];
    __syncthreads();
    if (tid < 64 && row0 + tid < N_NODES) {
        float as = 0.f, ad = 0.f;
#pragma unroll
        for (int c = 0; c < 40; ++c) {
            float v = hs[tid][c];
            as = fmaf(v, a_src[c], as);
            ad = fmaf(v, a_dst[c], ad);
        }
        ssrc[row0 + tid] = as;
        sdst[row0 + tid] = ad;
    }
}

// ---------------- layer 2 gather + log_softmax: one wave per node (bf16) ----
__global__ void gather2_kernel(const uint32* __restrict__ h2b,  // N x 20 uints
                               const float* __restrict__ ssrc,
                               const float* __restrict__ sdst,
                               const int* __restrict__ offsets,
                               const int* __restrict__ srcs,
                               const float* __restrict__ b2,
                               float* __restrict__ out)
{
    int d = (blockIdx.x * blockDim.x + threadIdx.x) >> 6;
    int lane = threadIdx.x & 63;
    if (d >= N_NODES) return;
    const float sd = sdst[d];
    const int g = lane / 20;              // group 0..2 (3 = idle tail lanes)
    const int c = lane - 20 * g;          // dword within row (channels 2c,2c+1)
    const bool act = lane < (NCLS / 2);   // lanes that own the output
    float acc0 = 0.f, acc1 = 0.f, ws = 0.f;

    // self-loop (group 0 only)
    {
        float lg = ssrc[d] + sd; lg = lg >= 0.f ? lg : NEG * lg;
        float w = __expf(lg);
        uint32 p = act ? h2b[(size_t)d * 20 + lane] : 0u;
        float m = act ? w : 0.f;
        acc0 = m * bf_lo(p); acc1 = m * bf_hi(p);
        ws = w;
    }
    const int beg = offsets[d], end = offsets[d + 1];
    for (int base = beg; base < end; base += 64) {
        int cnt = end - base; if (cnt > 64) cnt = 64;
        int s_l = 0; float w_l = 0.f;
        if (lane < cnt) {
            s_l = srcs[base + lane];
            float lg = ssrc[s_l] + sd; lg = lg >= 0.f ? lg : NEG * lg;
            w_l = __expf(lg);
        }
        float t = w_l;
#pragma unroll
        for (int o = 32; o > 0; o >>= 1) t += __shfl_xor(t, o);
        ws += t;
        for (int j = 0; j < cnt; j += 3) {
            int jj = j + g;
            int s = __shfl(s_l, jj & 63);
            float w = __shfl(w_l, jj & 63);
            if (g >= 3 || jj >= cnt) w = 0.f;
            uint32 p = h2b[(size_t)s * 20 + c];
            acc0 = fmaf(w, bf_lo(p), acc0);
            acc1 = fmaf(w, bf_hi(p), acc1);
        }
    }
    // cross-group reduce: groups live at lanes c, c+20, c+40
    float r00 = __shfl(acc0, lane + 20), r01 = __shfl(acc0, lane + 40);
    float r10 = __shfl(acc1, lane + 20), r11 = __shfl(acc1, lane + 40);
    float l0 = -INFINITY, l1 = -INFINITY;
    if (act) {
        acc0 += r00 + r01;
        acc1 += r10 + r11;
        float inv = 1.f / (ws + 1e-16f);
        l0 = fmaf(acc0, inv, b2[2 * lane]);
        l1 = fmaf(acc1, inv, b2[2 * lane + 1]);
    }
    float m = fmaxf(l0, l1);
#pragma unroll
    for (int o = 32; o > 0; o >>= 1) m = fmaxf(m, __shfl_xor(m, o));
    float ex = act ? (__expf(l0 - m) + __expf(l1 - m)) : 0.f;
#pragma unroll
    for (int o = 32; o > 0; o >>= 1) ex += __shfl_xor(ex, o);
    float lse = __logf(ex) + m;
    if (act) {
        float2 r; r.x = l0 - lse; r.y = l1 - lse;
        ((float2*)(out + (size_t)d * NCLS))[lane] = r;
    }
}

extern "C" void kernel_launch(void* const* d_in, const int* in_sizes, int n_in,
                              void* d_out, int out_size, void* d_ws, size_t ws_size,
                              hipStream_t stream)
{
    const float* x   = (const float*)d_in[0];
    const int*   ei  = (const int*)  d_in[1];
    const float* W1  = (const float*)d_in[2];
    const float* as1 = (const float*)d_in[3];
    const float* ad1 = (const float*)d_in[4];
    const float* b1  = (const float*)d_in[5];
    const float* W2  = (const float*)d_in[6];
    const float* as2 = (const float*)d_in[7];
    const float* ad2 = (const float*)d_in[8];
    const float* b2  = (const float*)d_in[9];
    float* out = (float*)d_out;
    const int E = in_sizes[1] / 2;

    float* ws = (float*)d_ws;
    size_t off = 0;
    uint32* h1f8 = (uint32*)(ws + off); off += (size_t)N_NODES * 32;  // fp8 N x 128
    float* h1r  = ws + off; off += (size_t)N_NODES * D1;
    float* ss1  = ws + off; off += (size_t)N_NODES * H1;
    float* sd1  = ws + off; off += (size_t)N_NODES * H1;
    uint32* h2b = (uint32*)(ws + off); off += (size_t)N_NODES * 20;   // bf16 N x 40
    float* ss2  = ws + off; off += N_NODES;
    float* sd2  = ws + off; off += N_NODES;
    int* ib = (int*)(ws + off);
    size_t ioff = 0;
    int* deg     = ib + ioff; ioff += N_NODES;      // must be zeroed
    int* incl    = ib + ioff; ioff += N_NODES;
    int* offsets = ib + ioff; ioff += N_NODES + 1;
    int* bsum    = ib + ioff; ioff += 512;
    int* rank    = ib + ioff; ioff += E;
    int* srcs    = ib + ioff; ioff += E;

    hipMemsetAsync(deg, 0, (size_t)N_NODES * sizeof(int), stream);

    const int nb = (N_NODES + 255) / 256;           // 391

    // fused layer-1 gemm(+logits) + CSR count (uniform blocks; NG*1024 >= E)
    gemm1_count_kernel<<<NG, 256, 0, stream>>>(x, W1, h1f8, as1, ad1,
                                               ss1, sd1, ei, E, deg, rank);
    // CSR finish (scan2 absorbed into scan3)
    scan1_kernel<<<nb, 256, 0, stream>>>(deg, incl, bsum);
    scan3_kernel<<<nb, 256, 0, stream>>>(incl, bsum, offsets);
    scatter_kernel<<<(E + 255) / 256, 256, 0, stream>>>(ei, E, offsets, rank, srcs);

    // layer 1 gather
    gather1_kernel<<<(N_NODES * 64 + 255) / 256, 256, 0, stream>>>(h1f8, ss1, sd1, offsets, srcs, b1, h1r);

    // layer 2 (gemm + logits fused)
    gemm2_kernel<<<(N_NODES + 63) / 64, 256, 0, stream>>>(h1r, W2, (ushort16*)h2b, as2, ad2, ss2, sd2);
    gather2_kernel<<<(N_NODES * 64 + 255) / 256, 256, 0, stream>>>(h2b, ss2, sd2, offsets, srcs, b2, out);
}